// Round 10
// baseline (87.178 us; speedup 1.0000x reference)
//
#include <hip/hip_runtime.h>
#include <hip/hip_bf16.h>

typedef short bf16x8 __attribute__((ext_vector_type(8)));
typedef float f32x4 __attribute__((ext_vector_type(4)));

typedef __attribute__((address_space(3))) void as3_void;
typedef const __attribute__((address_space(1))) void as1_void;

static constexpr int D = 256;
static constexpr float INV_T = 10.0f;  // 1 / 0.1

__device__ __forceinline__ ushort f2bf(float f) {
  union { float f; unsigned u; } v; v.f = f;
  unsigned r = v.u + 0x7fffu + ((v.u >> 16) & 1u);  // RNE
  return (ushort)(r >> 16);
}

// Kernel 1: L2-normalize rows of images & captions -> bf16; diag logits (fp32).
__global__ __launch_bounds__(256) void normalize_kernel(
    const float* __restrict__ im, const float* __restrict__ cap,
    ushort* __restrict__ imn, ushort* __restrict__ capn,
    float* __restrict__ diag, int N) {
  int tid = blockIdx.x * 256 + threadIdx.x;
  int w = tid >> 6;
  int lane = threadIdx.x & 63;
  if (w >= N) return;
  float4 vi = ((const float4*)(im + (size_t)w * D))[lane];
  float4 vc = ((const float4*)(cap + (size_t)w * D))[lane];
  float ssi = vi.x*vi.x + vi.y*vi.y + vi.z*vi.z + vi.w*vi.w;
  float ssc = vc.x*vc.x + vc.y*vc.y + vc.z*vc.z + vc.w*vc.w;
  #pragma unroll
  for (int m = 1; m < 64; m <<= 1) {
    ssi += __shfl_xor(ssi, m);
    ssc += __shfl_xor(ssc, m);
  }
  float ri = 1.0f / fmaxf(sqrtf(ssi), 1e-12f);
  float rc = 1.0f / fmaxf(sqrtf(ssc), 1e-12f);
  float ax = vi.x*ri, ay = vi.y*ri, az = vi.z*ri, aw = vi.w*ri;
  float cx = vc.x*rc, cy = vc.y*rc, cz = vc.z*rc, cw = vc.w*rc;
  ushort4 ua, uc;
  ua.x = f2bf(ax); ua.y = f2bf(ay); ua.z = f2bf(az); ua.w = f2bf(aw);
  uc.x = f2bf(cx); uc.y = f2bf(cy); uc.z = f2bf(cz); uc.w = f2bf(cw);
  ((ushort4*)(imn + (size_t)w * D))[lane] = ua;
  ((ushort4*)(capn + (size_t)w * D))[lane] = uc;
  float d = ax*cx + ay*cy + az*cz + aw*cw;
  #pragma unroll
  for (int m = 1; m < 64; m <<= 1) d += __shfl_xor(d, m);
  if (lane == 0) diag[w] = d * INV_T;
}

// Kernel 2: A-in-registers GEMM (flash-attn structure for K=256).
// Block = 8 waves x 32 private A-rows (BM=256); grid 512 = 32 bm x 16 grp;
// each block does 8 bn-tiles of 64 cols. A: 16 bf16x8/lane loaded once from
// global (frag layout, no LDS). B: 64x256 tile in LDS, double-buffered
// (2x32KB), gload_lds staged with the r6-verified swizzle (0 conflicts):
// LDS slot (col,u16) holds global u^(col&7); pre-swizzled source, same XOR
// on reads. Inner ks-loop barrier-FREE; 2 barriers per tile. VGPR capped 128
// -> 2 blocks/CU, 4 waves/SIMD: TLP covers all latency (m114 mechanism).
__global__ __launch_bounds__(512, 4) void gemm_exp_kernel(
    const ushort* __restrict__ A, const ushort* __restrict__ Bm,
    float* __restrict__ rowpart, float* __restrict__ colpart, int N) {
  __shared__ ushort Bsh[2][64 * 256];   // 2 x 32 KB
  __shared__ float colred[2][8][64];    // 4 KB, dbuf by tile parity
  int bm = blockIdx.x >> 4;
  int grp = blockIdx.x & 15;
  int t = threadIdx.x;
  int lane = t & 63;
  int wv = t >> 6;
  int rb = lane & 15;
  int hi = lane >> 4;
  int xr = rb & 7;

  // A fragments in registers: rows bm*256 + wv*32 + mi*16 + rb, 16B per (mi,ks)
  bf16x8 Areg[2][8];
  {
    const ushort* a0 = A + (size_t)(bm * 256 + wv * 32 + rb) * 256 + hi * 8;
    #pragma unroll
    for (int mi = 0; mi < 2; ++mi)
      #pragma unroll
      for (int ks = 0; ks < 8; ++ks)
        Areg[mi][ks] = *(const bf16x8*)(a0 + (size_t)mi * 16 * 256 + ks * 32);
  }

  // staging geometry: per q (0..3), lane writes LDS linear col = q*16 + scr,
  // u16 = lane&31; global source u pre-swizzled ^ (col&7) = ^(scr&7).
  int scr = wv * 2 + (lane >> 5);
  int su = (lane & 31) ^ (scr & 7);

  f32x4 acc[2][4];

#define VMWAIT(n) asm volatile("s_waitcnt vmcnt(" #n ")" ::: "memory")
#define BARRIER() asm volatile("s_barrier" ::: "memory")

#define STAGE(buf, j) {                                                       \
    const ushort* bsrc = Bm + ((size_t)((grp * 8 + (j)) * 64 + scr)) * 256 + su * 8; \
    _Pragma("unroll")                                                         \
    for (int q = 0; q < 4; ++q)                                               \
      __builtin_amdgcn_global_load_lds((as1_void*)(bsrc + (size_t)q * 16 * 256), \
          (as3_void*)(&Bsh[buf][q * 4096 + wv * 512]), 16, 0, 0);             \
  }

  // barrier-free inner loop: 8 ks x {4 swizzled b128 reads; 8 MFMA}; acc
  // restart via C=0 at ks==0.
#define COMPUTE(buf) {                                                        \
    _Pragma("unroll")                                                         \
    for (int ks = 0; ks < 8; ++ks) {                                          \
      bf16x8 bf[4];                                                           \
      _Pragma("unroll")                                                       \
      for (int ni = 0; ni < 4; ++ni)                                          \
        bf[ni] = *(const bf16x8*)(&Bsh[buf][(ni * 16 + rb) * 256 +            \
                                            (((ks * 4 + hi) ^ xr) * 8)]);     \
      __builtin_amdgcn_s_setprio(1);                                          \
      _Pragma("unroll")                                                       \
      for (int mi = 0; mi < 2; ++mi)                                          \
        _Pragma("unroll")                                                     \
        for (int ni = 0; ni < 4; ++ni)                                        \
          acc[mi][ni] = __builtin_amdgcn_mfma_f32_16x16x32_bf16(              \
              Areg[mi][ks], bf[ni],                                           \
              (ks == 0) ? (f32x4){0.f, 0.f, 0.f, 0.f} : acc[mi][ni], 0, 0, 0);\
      __builtin_amdgcn_s_setprio(0);                                          \
    }                                                                         \
  }

  // exp + row sums (packed butterfly) + per-wave col partials into colred
#define EPILOGUE(J) {                                                         \
    _Pragma("unroll")                                                         \
    for (int mi = 0; mi < 2; ++mi)                                            \
      _Pragma("unroll")                                                       \
      for (int ni = 0; ni < 4; ++ni)                                          \
        _Pragma("unroll")                                                     \
        for (int r = 0; r < 4; ++r)                                           \
          acc[mi][ni][r] = __expf(acc[mi][ni][r] * INV_T);                    \
    bool sb0 = (lane & 1) != 0, sb1 = (lane & 2) != 0;                        \
    _Pragma("unroll")                                                         \
    for (int mi = 0; mi < 2; ++mi) {                                          \
      float v0 = acc[mi][0][0] + acc[mi][1][0] + acc[mi][2][0] + acc[mi][3][0]; \
      float v1 = acc[mi][0][1] + acc[mi][1][1] + acc[mi][2][1] + acc[mi][3][1]; \
      float v2 = acc[mi][0][2] + acc[mi][1][2] + acc[mi][2][2] + acc[mi][3][2]; \
      float v3 = acc[mi][0][3] + acc[mi][1][3] + acc[mi][2][3] + acc[mi][3][3]; \
      float h0 = (sb0 ? v1 : v0) + __shfl_xor(sb0 ? v0 : v1, 1);              \
      float h1 = (sb0 ? v3 : v2) + __shfl_xor(sb0 ? v2 : v3, 1);              \
      float g  = (sb1 ? h1 : h0) + __shfl_xor(sb1 ? h0 : h1, 2);              \
      g += __shfl_xor(g, 4);                                                  \
      g += __shfl_xor(g, 8);                                                  \
      if ((lane & 12) == 0)                                                   \
        rowpart[(size_t)(grp * 8 + (J)) * N + bm * 256 + wv * 32 + mi * 16 +  \
                (lane >> 4) * 4 + (lane & 3)] = g;                            \
    }                                                                         \
    _Pragma("unroll")                                                         \
    for (int ni = 0; ni < 4; ++ni) {                                          \
      float v = 0.f;                                                          \
      _Pragma("unroll")                                                       \
      for (int mi = 0; mi < 2; ++mi)                                          \
        _Pragma("unroll")                                                     \
        for (int r = 0; r < 4; ++r)                                           \
          v += acc[mi][ni][r];                                                \
      v += __shfl_xor(v, 16); v += __shfl_xor(v, 32);                         \
      if (lane < 16) colred[(J) & 1][wv][ni * 16 + lane] = v;                 \
    }                                                                         \
  }

  // cross-wave col combine for tile J (reads colred[J&1]; race-free: writes
  // of J are 2 barriers back; next write to this parity is after next BAR).
#define COMBINE(J) {                                                          \
    if (wv == 0) {                                                            \
      float cs = 0.f;                                                         \
      _Pragma("unroll")                                                       \
      for (int w8 = 0; w8 < 8; ++w8) cs += colred[(J) & 1][w8][lane];         \
      colpart[(size_t)bm * N + (grp * 8 + (J)) * 64 + lane] = cs;             \
    }                                                                         \
  }

  // Prologue: A (16 loads) + B tiles 0,1 (4 loads each)
  STAGE(0, 0)
  STAGE(1, 1)
  VMWAIT(4); BARRIER();   // A + tile0 resident; tile1 in flight

  // body J: compute; BAR; stage(J+2); epilogue(J); combine(J-1); vmw; BAR
  COMPUTE(0) BARRIER(); STAGE(0, 2) EPILOGUE(0)              VMWAIT(4); BARRIER();
  COMPUTE(1) BARRIER(); STAGE(1, 3) EPILOGUE(1) COMBINE(0)   VMWAIT(4); BARRIER();
  COMPUTE(0) BARRIER(); STAGE(0, 4) EPILOGUE(2) COMBINE(1)   VMWAIT(4); BARRIER();
  COMPUTE(1) BARRIER(); STAGE(1, 5) EPILOGUE(3) COMBINE(2)   VMWAIT(4); BARRIER();
  COMPUTE(0) BARRIER(); STAGE(0, 6) EPILOGUE(4) COMBINE(3)   VMWAIT(4); BARRIER();
  COMPUTE(1) BARRIER(); STAGE(1, 7) EPILOGUE(5) COMBINE(4)   VMWAIT(4); BARRIER();
  COMPUTE(0) BARRIER();             EPILOGUE(6) COMBINE(5)   VMWAIT(0); BARRIER();
  COMPUTE(1) BARRIER();             EPILOGUE(7) COMBINE(6)
  BARRIER();
  COMBINE(7)

#undef COMBINE
#undef EPILOGUE
#undef COMPUTE
#undef STAGE
#undef VMWAIT
#undef BARRIER
}

// Kernel 3: partial reduction + per-sample loss + atomic accumulate into out.
// rowpart: 128 slots; colpart: 32 slots. d_out zeroed by hipMemsetAsync.
__global__ __launch_bounds__(256) void reduce_kernel(
    const float* __restrict__ rowpart, const float* __restrict__ colpart,
    const float* __restrict__ diag, float* __restrict__ out,
    int N, int NPr, int NPc) {
  __shared__ float redr[4][64], redc[4][64], redl[1];
  int w = threadIdx.x >> 6, s = threadIdx.x & 63;
  int i = blockIdx.x * 64 + s;
  float rs = 0.f, cs = 0.f;
  for (int k = w; k < NPr; k += 4) rs += rowpart[(size_t)k * N + i];
  for (int k = w; k < NPc; k += 4) cs += colpart[(size_t)k * N + i];
  redr[w][s] = rs; redc[w][s] = cs;
  __syncthreads();
  if (w == 0) {
    float R = redr[0][s] + redr[1][s] + redr[2][s] + redr[3][s];
    float C = redc[0][s] + redc[1][s] + redc[2][s] + redc[3][s];
    float l = logf(R) + logf(C) - 2.0f * diag[i];
    #pragma unroll
    for (int m = 1; m < 64; m <<= 1) l += __shfl_xor(l, m);
    if (s == 0) atomicAdd(out, l * (0.5f / (float)N));
  }
}

extern "C" void kernel_launch(void* const* d_in, const int* in_sizes, int n_in,
                              void* d_out, int out_size, void* d_ws, size_t ws_size,
                              hipStream_t stream) {
  const float* images = (const float*)d_in[0];
  const float* captions = (const float*)d_in[1];
  int N = in_sizes[0] / D;   // 8192
  int NPr = 128;             // 128 bn-tiles of 64 cols
  int NPc = 32;              // 32 bm-blocks (per-block pre-combined)
  char* w = (char*)d_ws;
  size_t off = 0;
  ushort* imn  = (ushort*)(w + off); off += (size_t)N * D * 2;
  ushort* capn = (ushort*)(w + off); off += (size_t)N * D * 2;
  float* diag    = (float*)(w + off); off += (size_t)N * 4;
  float* rowpart = (float*)(w + off); off += (size_t)NPr * N * 4;
  float* colpart = (float*)(w + off); off += (size_t)NPc * N * 4;
  float* out = (float*)d_out;

  normalize_kernel<<<N / 4, 256, 0, stream>>>(images, captions, imn, capn, diag, N);
  gemm_exp_kernel<<<512, 512, 0, stream>>>(imn, capn, rowpart, colpart, N);
  hipMemsetAsync(out, 0, sizeof(float), stream);
  reduce_kernel<<<N / 64, 256, 0, stream>>>(rowpart, colpart, diag, out, N, NPr, NPc);
}

// Round 11
// 76.065 us; speedup vs baseline: 1.1461x; 1.1461x over previous
//
#include <hip/hip_runtime.h>
#include <hip/hip_bf16.h>

typedef short bf16x8 __attribute__((ext_vector_type(8)));
typedef float f32x4 __attribute__((ext_vector_type(4)));

typedef __attribute__((address_space(3))) void as3_void;
typedef const __attribute__((address_space(1))) void as1_void;

static constexpr int D = 256;
static constexpr float INV_T = 10.0f;  // 1 / 0.1

__device__ __forceinline__ ushort f2bf(float f) {
  union { float f; unsigned u; } v; v.f = f;
  unsigned r = v.u + 0x7fffu + ((v.u >> 16) & 1u);  // RNE
  return (ushort)(r >> 16);
}

// Kernel 1: L2-normalize rows of images & captions -> bf16; diag logits (fp32).
__global__ __launch_bounds__(256) void normalize_kernel(
    const float* __restrict__ im, const float* __restrict__ cap,
    ushort* __restrict__ imn, ushort* __restrict__ capn,
    float* __restrict__ diag, int N) {
  int tid = blockIdx.x * 256 + threadIdx.x;
  int w = tid >> 6;
  int lane = threadIdx.x & 63;
  if (w >= N) return;
  float4 vi = ((const float4*)(im + (size_t)w * D))[lane];
  float4 vc = ((const float4*)(cap + (size_t)w * D))[lane];
  float ssi = vi.x*vi.x + vi.y*vi.y + vi.z*vi.z + vi.w*vi.w;
  float ssc = vc.x*vc.x + vc.y*vc.y + vc.z*vc.z + vc.w*vc.w;
  #pragma unroll
  for (int m = 1; m < 64; m <<= 1) {
    ssi += __shfl_xor(ssi, m);
    ssc += __shfl_xor(ssc, m);
  }
  float ri = 1.0f / fmaxf(sqrtf(ssi), 1e-12f);
  float rc = 1.0f / fmaxf(sqrtf(ssc), 1e-12f);
  float ax = vi.x*ri, ay = vi.y*ri, az = vi.z*ri, aw = vi.w*ri;
  float cx = vc.x*rc, cy = vc.y*rc, cz = vc.z*rc, cw = vc.w*rc;
  ushort4 ua, uc;
  ua.x = f2bf(ax); ua.y = f2bf(ay); ua.z = f2bf(az); ua.w = f2bf(aw);
  uc.x = f2bf(cx); uc.y = f2bf(cy); uc.z = f2bf(cz); uc.w = f2bf(cw);
  ((ushort4*)(imn + (size_t)w * D))[lane] = ua;
  ((ushort4*)(capn + (size_t)w * D))[lane] = uc;
  float d = ax*cx + ay*cy + az*cz + aw*cw;
  #pragma unroll
  for (int m = 1; m < 64; m <<= 1) d += __shfl_xor(d, m);
  if (lane == 0) diag[w] = d * INV_T;
}

// Kernel 2: A-in-registers GEMM. Block = 8 waves x 32 private A-rows (BM=256);
// grid 512 = 32 bm x 16 grp; 8 bn-tiles of 64 cols each. A: 16 bf16x8/lane
// loaded once (global, frag layout). B: tile as 8 K-slices in LDS, each the
// r6-VERIFIED [64 col][32 elem] layout (64B rows; involution u^((row>>1)&3);
// measured 0 bank conflicts). Double-buffered: 2x32KB + colred 4KB = 68KB
// -> with VGPR<=128 (launch_bounds(512,2) == min 2 BLOCKS/CU, CUDA semantics
// per r7/r10 evidence) => 2 blocks/CU, 4 waves/SIMD: TLP covers latency.
// Barrier-free inner ks-loop; 2 barriers/tile; counted vmcnt(4) (stores are
// issued BEFORE the stage quartet so vmcnt(4) == newest stage for all waves).
__global__ __launch_bounds__(512, 2) void gemm_exp_kernel(
    const ushort* __restrict__ A, const ushort* __restrict__ Bm,
    float* __restrict__ rowpart, float* __restrict__ colpart, int N) {
  __shared__ ushort Bsh[2][8 * 64 * 32];  // 2 x 32 KB (8 K-slices of [64][32])
  __shared__ float colred[2][8][64];      // 4 KB, dbuf by tile parity
  int bm = blockIdx.x >> 4;
  int grp = blockIdx.x & 15;
  int lane = threadIdx.x & 63;
  int wv = threadIdx.x >> 6;
  int rb = lane & 15;
  int hi = lane >> 4;

  // A fragments: rows bm*256 + wv*32 + mi*16 + rb; Areg[mi][ks] = 16B at
  // k = ks*32 + hi*8  (matches MFMA A-frag layout used since r2, absmax=0).
  bf16x8 Areg[2][8];
  {
    const ushort* a0 = A + (size_t)(bm * 256 + wv * 32 + rb) * 256 + hi * 8;
    #pragma unroll
    for (int mi = 0; mi < 2; ++mi)
      #pragma unroll
      for (int ks = 0; ks < 8; ++ks)
        Areg[mi][ks] = *(const bf16x8*)(a0 + (size_t)mi * 16 * 256 + ks * 32);
  }

  // Staging geometry: wave wv owns K-slice wv; 4 chunks of 16 cols. Lane:
  // col-in-chunk = lane>>2, unit u' = lane&3 (LDS linear: dest = wv*2048 +
  // c*512 + lane*8 elems). Global source unit = u' ^ ((col>>1)&3)
  //                                           = (lane&3) ^ ((lane>>3)&3).
  int sj = lane >> 2;
  int su = (lane & 3) ^ ((lane >> 3) & 3);
  int soff = sj * 256 + wv * 32 + su * 8;   // per-lane source offset (elems)

  f32x4 acc[2][4];
  // Read column within a slice row (r6-verified): cc = (hi ^ ((rb>>1)&3))*8
  int cc = (hi ^ ((rb >> 1) & 3)) * 8;

#define VMWAIT(n) asm volatile("s_waitcnt vmcnt(" #n ")" ::: "memory")
#define BARRIER() asm volatile("s_barrier" ::: "memory")

#define STAGE(buf, J) {                                                       \
    const ushort* bsrc = Bm + (size_t)((grp * 8 + (J)) * 64) * 256 + soff;    \
    _Pragma("unroll")                                                         \
    for (int c = 0; c < 4; ++c)                                               \
      __builtin_amdgcn_global_load_lds(                                       \
          (as1_void*)(bsrc + (size_t)c * 16 * 256),                           \
          (as3_void*)(&Bsh[buf][wv * 2048 + c * 512 + lane * 8]), 16, 0, 0);  \
  }

#define RDB(b, buf, ks, ni)                                                   \
  b = *(const bf16x8*)(&Bsh[buf][((ks) * 64 + (ni) * 16 + rb) * 32 + cc]);

  // barrier-free inner loop; B frags consumed in pairs (register economy);
  // acc restart via C=0 at ks==0.
#define COMPUTE(buf) {                                                        \
    _Pragma("unroll")                                                         \
    for (int ks = 0; ks < 8; ++ks) {                                          \
      bf16x8 b0, b1;                                                          \
      RDB(b0, buf, ks, 0) RDB(b1, buf, ks, 1)                                 \
      __builtin_amdgcn_s_setprio(1);                                          \
      acc[0][0] = __builtin_amdgcn_mfma_f32_16x16x32_bf16(Areg[0][ks], b0,    \
          (ks == 0) ? (f32x4){0.f,0.f,0.f,0.f} : acc[0][0], 0, 0, 0);         \
      acc[1][0] = __builtin_amdgcn_mfma_f32_16x16x32_bf16(Areg[1][ks], b0,    \
          (ks == 0) ? (f32x4){0.f,0.f,0.f,0.f} : acc[1][0], 0, 0, 0);         \
      acc[0][1] = __builtin_amdgcn_mfma_f32_16x16x32_bf16(Areg[0][ks], b1,    \
          (ks == 0) ? (f32x4){0.f,0.f,0.f,0.f} : acc[0][1], 0, 0, 0);         \
      acc[1][1] = __builtin_amdgcn_mfma_f32_16x16x32_bf16(Areg[1][ks], b1,    \
          (ks == 0) ? (f32x4){0.f,0.f,0.f,0.f} : acc[1][1], 0, 0, 0);         \
      __builtin_amdgcn_s_setprio(0);                                          \
      RDB(b0, buf, ks, 2) RDB(b1, buf, ks, 3)                                 \
      __builtin_amdgcn_s_setprio(1);                                          \
      acc[0][2] = __builtin_amdgcn_mfma_f32_16x16x32_bf16(Areg[0][ks], b0,    \
          (ks == 0) ? (f32x4){0.f,0.f,0.f,0.f} : acc[0][2], 0, 0, 0);         \
      acc[1][2] = __builtin_amdgcn_mfma_f32_16x16x32_bf16(Areg[1][ks], b0,    \
          (ks == 0) ? (f32x4){0.f,0.f,0.f,0.f} : acc[1][2], 0, 0, 0);         \
      acc[0][3] = __builtin_amdgcn_mfma_f32_16x16x32_bf16(Areg[0][ks], b1,    \
          (ks == 0) ? (f32x4){0.f,0.f,0.f,0.f} : acc[0][3], 0, 0, 0);         \
      acc[1][3] = __builtin_amdgcn_mfma_f32_16x16x32_bf16(Areg[1][ks], b1,    \
          (ks == 0) ? (f32x4){0.f,0.f,0.f,0.f} : acc[1][3], 0, 0, 0);         \
      __builtin_amdgcn_s_setprio(0);                                          \
    }                                                                         \
  }

  // exp + row sums (packed butterfly) + per-wave col partials into colred.
#define EPILOGUE(J) {                                                         \
    _Pragma("unroll")                                                         \
    for (int mi = 0; mi < 2; ++mi)                                            \
      _Pragma("unroll")                                                       \
      for (int ni = 0; ni < 4; ++ni)                                          \
        _Pragma("unroll")                                                     \
        for (int r = 0; r < 4; ++r)                                           \
          acc[mi][ni][r] = __expf(acc[mi][ni][r] * INV_T);                    \
    bool sb0 = (lane & 1) != 0, sb1 = (lane & 2) != 0;                        \
    _Pragma("unroll")                                                         \
    for (int mi = 0; mi < 2; ++mi) {                                          \
      float v0 = acc[mi][0][0] + acc[mi][1][0] + acc[mi][2][0] + acc[mi][3][0]; \
      float v1 = acc[mi][0][1] + acc[mi][1][1] + acc[mi][2][1] + acc[mi][3][1]; \
      float v2 = acc[mi][0][2] + acc[mi][1][2] + acc[mi][2][2] + acc[mi][3][2]; \
      float v3 = acc[mi][0][3] + acc[mi][1][3] + acc[mi][2][3] + acc[mi][3][3]; \
      float h0 = (sb0 ? v1 : v0) + __shfl_xor(sb0 ? v0 : v1, 1);              \
      float h1 = (sb0 ? v3 : v2) + __shfl_xor(sb0 ? v2 : v3, 1);              \
      float g  = (sb1 ? h1 : h0) + __shfl_xor(sb1 ? h0 : h1, 2);              \
      g += __shfl_xor(g, 4);                                                  \
      g += __shfl_xor(g, 8);                                                  \
      if ((lane & 12) == 0)                                                   \
        rowpart[(size_t)(grp * 8 + (J)) * N + bm * 256 + wv * 32 + mi * 16 +  \
                (lane >> 4) * 4 + (lane & 3)] = g;                            \
    }                                                                         \
    _Pragma("unroll")                                                         \
    for (int ni = 0; ni < 4; ++ni) {                                          \
      float v = 0.f;                                                          \
      _Pragma("unroll")                                                       \
      for (int mi = 0; mi < 2; ++mi)                                          \
        _Pragma("unroll")                                                     \
        for (int r = 0; r < 4; ++r)                                           \
          v += acc[mi][ni][r];                                                \
      v += __shfl_xor(v, 16); v += __shfl_xor(v, 32);                         \
      if (lane < 16) colred[(J) & 1][wv][ni * 16 + lane] = v;                 \
    }                                                                         \
  }

#define COMBINE(J) {                                                          \
    if (wv == 0) {                                                            \
      float cs = 0.f;                                                         \
      _Pragma("unroll")                                                       \
      for (int w8 = 0; w8 < 8; ++w8) cs += colred[(J) & 1][w8][lane];         \
      colpart[(size_t)bm * N + (grp * 8 + (J)) * 64 + lane] = cs;             \
    }                                                                         \
  }

  // Prologue: tiles 0,1 staged (A loads complete under compiler's own waits)
  STAGE(0, 0)
  STAGE(1, 1)
  VMWAIT(4); BARRIER();   // tile0 resident; tile1 (newest 4) in flight

  // body J: COMPUTE(J); BAR (buf free); EPILOGUE; COMBINE(J-1); STAGE(J+2);
  // vmcnt(4) (completes tile J+1 + all stores; leaves the J+2 quartet); BAR.
  COMPUTE(0) BARRIER(); EPILOGUE(0)            STAGE(0, 2) VMWAIT(4); BARRIER();
  COMPUTE(1) BARRIER(); EPILOGUE(1) COMBINE(0) STAGE(1, 3) VMWAIT(4); BARRIER();
  COMPUTE(0) BARRIER(); EPILOGUE(2) COMBINE(1) STAGE(0, 4) VMWAIT(4); BARRIER();
  COMPUTE(1) BARRIER(); EPILOGUE(3) COMBINE(2) STAGE(1, 5) VMWAIT(4); BARRIER();
  COMPUTE(0) BARRIER(); EPILOGUE(4) COMBINE(3) STAGE(0, 6) VMWAIT(4); BARRIER();
  COMPUTE(1) BARRIER(); EPILOGUE(5) COMBINE(4) STAGE(1, 7) VMWAIT(4); BARRIER();
  COMPUTE(0) BARRIER(); EPILOGUE(6) COMBINE(5)             VMWAIT(0); BARRIER();
  COMPUTE(1) BARRIER(); EPILOGUE(7) COMBINE(6)
  BARRIER();
  COMBINE(7)

#undef COMBINE
#undef EPILOGUE
#undef COMPUTE
#undef RDB
#undef STAGE
#undef VMWAIT
#undef BARRIER
}

// Kernel 3: partial reduction + per-sample loss + atomic accumulate into out.
__global__ __launch_bounds__(256) void reduce_kernel(
    const float* __restrict__ rowpart, const float* __restrict__ colpart,
    const float* __restrict__ diag, float* __restrict__ out,
    int N, int NPr, int NPc) {
  __shared__ float redr[4][64], redc[4][64];
  int w = threadIdx.x >> 6, s = threadIdx.x & 63;
  int i = blockIdx.x * 64 + s;
  float rs = 0.f, cs = 0.f;
  for (int k = w; k < NPr; k += 4) rs += rowpart[(size_t)k * N + i];
  for (int k = w; k < NPc; k += 4) cs += colpart[(size_t)k * N + i];
  redr[w][s] = rs; redc[w][s] = cs;
  __syncthreads();
  if (w == 0) {
    float R = redr[0][s] + redr[1][s] + redr[2][s] + redr[3][s];
    float C = redc[0][s] + redc[1][s] + redc[2][s] + redc[3][s];
    float l = logf(R) + logf(C) - 2.0f * diag[i];
    #pragma unroll
    for (int m = 1; m < 64; m <<= 1) l += __shfl_xor(l, m);
    if (s == 0) atomicAdd(out, l * (0.5f / (float)N));
  }
}

extern "C" void kernel_launch(void* const* d_in, const int* in_sizes, int n_in,
                              void* d_out, int out_size, void* d_ws, size_t ws_size,
                              hipStream_t stream) {
  const float* images = (const float*)d_in[0];
  const float* captions = (const float*)d_in[1];
  int N = in_sizes[0] / D;   // 8192
  int NPr = 128;             // 128 bn-tiles of 64 cols
  int NPc = 32;              // 32 bm-blocks (per-block pre-combined)
  char* w = (char*)d_ws;
  size_t off = 0;
  ushort* imn  = (ushort*)(w + off); off += (size_t)N * D * 2;
  ushort* capn = (ushort*)(w + off); off += (size_t)N * D * 2;
  float* diag    = (float*)(w + off); off += (size_t)N * 4;
  float* rowpart = (float*)(w + off); off += (size_t)NPr * N * 4;
  float* colpart = (float*)(w + off); off += (size_t)NPc * N * 4;
  float* out = (float*)d_out;

  normalize_kernel<<<N / 4, 256, 0, stream>>>(images, captions, imn, capn, diag, N);
  gemm_exp_kernel<<<512, 512, 0, stream>>>(imn, capn, rowpart, colpart, N);
  hipMemsetAsync(out, 0, sizeof(float), stream);
  reduce_kernel<<<N / 64, 256, 0, stream>>>(rowpart, colpart, diag, out, N, NPr, NPc);
}

// Round 12
// 72.793 us; speedup vs baseline: 1.1976x; 1.0449x over previous
//
#include <hip/hip_runtime.h>
#include <hip/hip_bf16.h>

typedef short bf16x8 __attribute__((ext_vector_type(8)));
typedef float f32x4 __attribute__((ext_vector_type(4)));

typedef __attribute__((address_space(3))) void as3_void;
typedef const __attribute__((address_space(1))) void as1_void;

static constexpr int D = 256;
static constexpr float INV_T = 10.0f;  // 1 / 0.1

__device__ __forceinline__ ushort f2bf(float f) {
  union { float f; unsigned u; } v; v.f = f;
  unsigned r = v.u + 0x7fffu + ((v.u >> 16) & 1u);  // RNE
  return (ushort)(r >> 16);
}

// Kernel 1: L2-normalize rows of images & captions -> bf16; diag logits (fp32).
__global__ __launch_bounds__(256) void normalize_kernel(
    const float* __restrict__ im, const float* __restrict__ cap,
    ushort* __restrict__ imn, ushort* __restrict__ capn,
    float* __restrict__ diag, int N) {
  int tid = blockIdx.x * 256 + threadIdx.x;
  int w = tid >> 6;
  int lane = threadIdx.x & 63;
  if (w >= N) return;
  float4 vi = ((const float4*)(im + (size_t)w * D))[lane];
  float4 vc = ((const float4*)(cap + (size_t)w * D))[lane];
  float ssi = vi.x*vi.x + vi.y*vi.y + vi.z*vi.z + vi.w*vi.w;
  float ssc = vc.x*vc.x + vc.y*vc.y + vc.z*vc.z + vc.w*vc.w;
  #pragma unroll
  for (int m = 1; m < 64; m <<= 1) {
    ssi += __shfl_xor(ssi, m);
    ssc += __shfl_xor(ssc, m);
  }
  float ri = 1.0f / fmaxf(sqrtf(ssi), 1e-12f);
  float rc = 1.0f / fmaxf(sqrtf(ssc), 1e-12f);
  float ax = vi.x*ri, ay = vi.y*ri, az = vi.z*ri, aw = vi.w*ri;
  float cx = vc.x*rc, cy = vc.y*rc, cz = vc.z*rc, cw = vc.w*rc;
  ushort4 ua, uc;
  ua.x = f2bf(ax); ua.y = f2bf(ay); ua.z = f2bf(az); ua.w = f2bf(aw);
  uc.x = f2bf(cx); uc.y = f2bf(cy); uc.z = f2bf(cz); uc.w = f2bf(cw);
  ((ushort4*)(imn + (size_t)w * D))[lane] = ua;
  ((ushort4*)(capn + (size_t)w * D))[lane] = uc;
  float d = ax*cx + ay*cy + az*cz + aw*cw;
  #pragma unroll
  for (int m = 1; m < 64; m <<= 1) d += __shfl_xor(d, m);
  if (lane == 0) diag[w] = d * INV_T;
}

// Kernel 2: A-in-registers GEMM (r11 structure) + two fixes:
//  (1) Areg PINNED via asm "+v" -- r11's VGPR_Count=72 < the 96 live proved
//      the compiler rematerialized A global loads inside every COMPUTE
//      (FETCH 12.5->18.6MB), injecting L2 latency into the MFMA loop.
//      asm-defined values cannot be rematerialized.
//  (2) B-frag read-ahead inside COMPUTE: quartet q+1's ds_reads issued
//      before quartet q's MFMAs -> MFMA waits only on quartet-old reads.
// Layout/swizzle/ledger identical to r11 (0 bank conflicts measured).
__global__ __launch_bounds__(512, 2) void gemm_exp_kernel(
    const ushort* __restrict__ A, const ushort* __restrict__ Bm,
    float* __restrict__ rowpart, float* __restrict__ colpart, int N) {
  __shared__ ushort Bsh[2][8 * 64 * 32];  // 2 x 32 KB (8 K-slices of [64][32])
  __shared__ float colred[2][8][64];      // 4 KB, dbuf by tile parity
  int bm = blockIdx.x >> 4;
  int grp = blockIdx.x & 15;
  int lane = threadIdx.x & 63;
  int wv = threadIdx.x >> 6;
  int rb = lane & 15;
  int hi = lane >> 4;

  // A fragments: rows bm*256 + wv*32 + mi*16 + rb; Areg[mi][ks] = 16B at
  // k = ks*32 + hi*8.
  bf16x8 Areg[2][8];
  {
    const ushort* a0 = A + (size_t)(bm * 256 + wv * 32 + rb) * 256 + hi * 8;
    #pragma unroll
    for (int mi = 0; mi < 2; ++mi)
      #pragma unroll
      for (int ks = 0; ks < 8; ++ks)
        Areg[mi][ks] = *(const bf16x8*)(a0 + (size_t)mi * 16 * 256 + ks * 32);
  }
  // PIN: asm-define each fragment so the loads cannot be rematerialized.
  #pragma unroll
  for (int mi = 0; mi < 2; ++mi)
    #pragma unroll
    for (int ks = 0; ks < 8; ++ks)
      asm volatile("" : "+v"(Areg[mi][ks]));

  // Staging geometry (r6-verified involution, 0 conflicts): wave wv owns
  // K-slice wv; LDS linear dest = wv*2048 + c*512 + lane*8 elems; global
  // source unit pre-swizzled (lane&3) ^ ((lane>>3)&3).
  int sj = lane >> 2;
  int su = (lane & 3) ^ ((lane >> 3) & 3);
  int soff = sj * 256 + wv * 32 + su * 8;

  f32x4 acc[2][4];
  int cc = (hi ^ ((rb >> 1) & 3)) * 8;  // swizzled read column (elems)

#define VMWAIT(n) asm volatile("s_waitcnt vmcnt(" #n ")" ::: "memory")
#define BARRIER() asm volatile("s_barrier" ::: "memory")

#define STAGE(buf, J) {                                                       \
    const ushort* bsrc = Bm + (size_t)((grp * 8 + (J)) * 64) * 256 + soff;    \
    _Pragma("unroll")                                                         \
    for (int c = 0; c < 4; ++c)                                               \
      __builtin_amdgcn_global_load_lds(                                       \
          (as1_void*)(bsrc + (size_t)c * 16 * 256),                           \
          (as3_void*)(&Bsh[buf][wv * 2048 + c * 512 + lane * 8]), 16, 0, 0);  \
  }

#define RDB(b, buf, ks, ni)                                                   \
  b = *(const bf16x8*)(&Bsh[buf][((ks) * 64 + (ni) * 16 + rb) * 32 + cc]);

#define QUAD(BF0, BF1, ks, nlo, Z)                                            \
  __builtin_amdgcn_s_setprio(1);                                              \
  acc[0][(nlo)]     = __builtin_amdgcn_mfma_f32_16x16x32_bf16(Areg[0][ks], BF0, \
      (Z) ? (f32x4){0.f,0.f,0.f,0.f} : acc[0][(nlo)], 0, 0, 0);               \
  acc[1][(nlo)]     = __builtin_amdgcn_mfma_f32_16x16x32_bf16(Areg[1][ks], BF0, \
      (Z) ? (f32x4){0.f,0.f,0.f,0.f} : acc[1][(nlo)], 0, 0, 0);               \
  acc[0][(nlo) + 1] = __builtin_amdgcn_mfma_f32_16x16x32_bf16(Areg[0][ks], BF1, \
      (Z) ? (f32x4){0.f,0.f,0.f,0.f} : acc[0][(nlo) + 1], 0, 0, 0);           \
  acc[1][(nlo) + 1] = __builtin_amdgcn_mfma_f32_16x16x32_bf16(Areg[1][ks], BF1, \
      (Z) ? (f32x4){0.f,0.f,0.f,0.f} : acc[1][(nlo) + 1], 0, 0, 0);           \
  __builtin_amdgcn_s_setprio(0);

  // barrier-free inner loop with one-quartet read-ahead: reads for the next
  // MFMA quartet are issued before the current quartet's MFMAs.
#define COMPUTE(buf) {                                                        \
    bf16x8 c0, c1, n0, n1;                                                    \
    RDB(c0, buf, 0, 0) RDB(c1, buf, 0, 1)                                     \
    _Pragma("unroll")                                                         \
    for (int ks = 0; ks < 8; ++ks) {                                          \
      RDB(n0, buf, ks, 2) RDB(n1, buf, ks, 3)                                 \
      QUAD(c0, c1, ks, 0, ks == 0)                                            \
      if (ks < 7) { RDB(c0, buf, ks + 1, 0) RDB(c1, buf, ks + 1, 1) }         \
      QUAD(n0, n1, ks, 2, ks == 0)                                            \
    }                                                                         \
  }

  // exp + row sums (packed butterfly) + per-wave col partials into colred.
#define EPILOGUE(J) {                                                         \
    _Pragma("unroll")                                                         \
    for (int mi = 0; mi < 2; ++mi)                                            \
      _Pragma("unroll")                                                       \
      for (int ni = 0; ni < 4; ++ni)                                          \
        _Pragma("unroll")                                                     \
        for (int r = 0; r < 4; ++r)                                           \
          acc[mi][ni][r] = __expf(acc[mi][ni][r] * INV_T);                    \
    bool sb0 = (lane & 1) != 0, sb1 = (lane & 2) != 0;                        \
    _Pragma("unroll")                                                         \
    for (int mi = 0; mi < 2; ++mi) {                                          \
      float v0 = acc[mi][0][0] + acc[mi][1][0] + acc[mi][2][0] + acc[mi][3][0]; \
      float v1 = acc[mi][0][1] + acc[mi][1][1] + acc[mi][2][1] + acc[mi][3][1]; \
      float v2 = acc[mi][0][2] + acc[mi][1][2] + acc[mi][2][2] + acc[mi][3][2]; \
      float v3 = acc[mi][0][3] + acc[mi][1][3] + acc[mi][2][3] + acc[mi][3][3]; \
      float h0 = (sb0 ? v1 : v0) + __shfl_xor(sb0 ? v0 : v1, 1);              \
      float h1 = (sb0 ? v3 : v2) + __shfl_xor(sb0 ? v2 : v3, 1);              \
      float g  = (sb1 ? h1 : h0) + __shfl_xor(sb1 ? h0 : h1, 2);              \
      g += __shfl_xor(g, 4);                                                  \
      g += __shfl_xor(g, 8);                                                  \
      if ((lane & 12) == 0)                                                   \
        rowpart[(size_t)(grp * 8 + (J)) * N + bm * 256 + wv * 32 + mi * 16 +  \
                (lane >> 4) * 4 + (lane & 3)] = g;                            \
    }                                                                         \
    _Pragma("unroll")                                                         \
    for (int ni = 0; ni < 4; ++ni) {                                          \
      float v = 0.f;                                                          \
      _Pragma("unroll")                                                       \
      for (int mi = 0; mi < 2; ++mi)                                          \
        _Pragma("unroll")                                                     \
        for (int r = 0; r < 4; ++r)                                           \
          v += acc[mi][ni][r];                                                \
      v += __shfl_xor(v, 16); v += __shfl_xor(v, 32);                         \
      if (lane < 16) colred[(J) & 1][wv][ni * 16 + lane] = v;                 \
    }                                                                         \
  }

#define COMBINE(J) {                                                          \
    if (wv == 0) {                                                            \
      float cs = 0.f;                                                         \
      _Pragma("unroll")                                                       \
      for (int w8 = 0; w8 < 8; ++w8) cs += colred[(J) & 1][w8][lane];         \
      colpart[(size_t)bm * N + (grp * 8 + (J)) * 64 + lane] = cs;             \
    }                                                                         \
  }

  // Prologue: tiles 0,1 staged.
  STAGE(0, 0)
  STAGE(1, 1)
  VMWAIT(4); BARRIER();   // tile0 resident; tile1 (newest 4) in flight

  // body J: COMPUTE(J); BAR (buf free); EPILOGUE; COMBINE(J-1); STAGE(J+2);
  // vmcnt(4) (tile J+1 resident + stores done; leaves J+2 quartet); BAR.
  COMPUTE(0) BARRIER(); EPILOGUE(0)            STAGE(0, 2) VMWAIT(4); BARRIER();
  COMPUTE(1) BARRIER(); EPILOGUE(1) COMBINE(0) STAGE(1, 3) VMWAIT(4); BARRIER();
  COMPUTE(0) BARRIER(); EPILOGUE(2) COMBINE(1) STAGE(0, 4) VMWAIT(4); BARRIER();
  COMPUTE(1) BARRIER(); EPILOGUE(3) COMBINE(2) STAGE(1, 5) VMWAIT(4); BARRIER();
  COMPUTE(0) BARRIER(); EPILOGUE(4) COMBINE(3) STAGE(0, 6) VMWAIT(4); BARRIER();
  COMPUTE(1) BARRIER(); EPILOGUE(5) COMBINE(4) STAGE(1, 7) VMWAIT(4); BARRIER();
  COMPUTE(0) BARRIER(); EPILOGUE(6) COMBINE(5)             VMWAIT(0); BARRIER();
  COMPUTE(1) BARRIER(); EPILOGUE(7) COMBINE(6)
  BARRIER();
  COMBINE(7)

#undef COMBINE
#undef EPILOGUE
#undef COMPUTE
#undef QUAD
#undef RDB
#undef STAGE
#undef VMWAIT
#undef BARRIER
}

// Kernel 3: partial reduction + per-sample loss + atomic accumulate into out.
__global__ __launch_bounds__(256) void reduce_kernel(
    const float* __restrict__ rowpart, const float* __restrict__ colpart,
    const float* __restrict__ diag, float* __restrict__ out,
    int N, int NPr, int NPc) {
  __shared__ float redr[4][64], redc[4][64];
  int w = threadIdx.x >> 6, s = threadIdx.x & 63;
  int i = blockIdx.x * 64 + s;
  float rs = 0.f, cs = 0.f;
  for (int k = w; k < NPr; k += 4) rs += rowpart[(size_t)k * N + i];
  for (int k = w; k < NPc; k += 4) cs += colpart[(size_t)k * N + i];
  redr[w][s] = rs; redc[w][s] = cs;
  __syncthreads();
  if (w == 0) {
    float R = redr[0][s] + redr[1][s] + redr[2][s] + redr[3][s];
    float C = redc[0][s] + redc[1][s] + redc[2][s] + redc[3][s];
    float l = logf(R) + logf(C) - 2.0f * diag[i];
    #pragma unroll
    for (int m = 1; m < 64; m <<= 1) l += __shfl_xor(l, m);
    if (s == 0) atomicAdd(out, l * (0.5f / (float)N));
  }
}

extern "C" void kernel_launch(void* const* d_in, const int* in_sizes, int n_in,
                              void* d_out, int out_size, void* d_ws, size_t ws_size,
                              hipStream_t stream) {
  const float* images = (const float*)d_in[0];
  const float* captions = (const float*)d_in[1];
  int N = in_sizes[0] / D;   // 8192
  int NPr = 128;             // 128 bn-tiles of 64 cols
  int NPc = 32;              // 32 bm-blocks (per-block pre-combined)
  char* w = (char*)d_ws;
  size_t off = 0;
  ushort* imn  = (ushort*)(w + off); off += (size_t)N * D * 2;
  ushort* capn = (ushort*)(w + off); off += (size_t)N * D * 2;
  float* diag    = (float*)(w + off); off += (size_t)N * 4;
  float* rowpart = (float*)(w + off); off += (size_t)NPr * N * 4;
  float* colpart = (float*)(w + off); off += (size_t)NPc * N * 4;
  float* out = (float*)d_out;

  normalize_kernel<<<N / 4, 256, 0, stream>>>(images, captions, imn, capn, diag, N);
  gemm_exp_kernel<<<512, 512, 0, stream>>>(imn, capn, rowpart, colpart, N);
  hipMemsetAsync(out, 0, sizeof(float), stream);
  reduce_kernel<<<N / 64, 256, 0, stream>>>(rowpart, colpart, diag, out, N, NPr, NPc);
}

// Round 13
// 70.623 us; speedup vs baseline: 1.2344x; 1.0307x over previous
//
#include <hip/hip_runtime.h>
#include <hip/hip_bf16.h>

typedef short bf16x8 __attribute__((ext_vector_type(8)));
typedef float f32x4 __attribute__((ext_vector_type(4)));

typedef __attribute__((address_space(3))) void as3_void;
typedef const __attribute__((address_space(1))) void as1_void;

static constexpr int D = 256;
static constexpr float INV_T = 10.0f;  // 1 / 0.1

__device__ __forceinline__ ushort f2bf(float f) {
  union { float f; unsigned u; } v; v.f = f;
  unsigned r = v.u + 0x7fffu + ((v.u >> 16) & 1u);  // RNE
  return (ushort)(r >> 16);
}

// Kernel 1: L2-normalize rows of images & captions -> bf16; diag logits (fp32).
__global__ __launch_bounds__(256) void normalize_kernel(
    const float* __restrict__ im, const float* __restrict__ cap,
    ushort* __restrict__ imn, ushort* __restrict__ capn,
    float* __restrict__ diag, int N) {
  int tid = blockIdx.x * 256 + threadIdx.x;
  int w = tid >> 6;
  int lane = threadIdx.x & 63;
  if (w >= N) return;
  float4 vi = ((const float4*)(im + (size_t)w * D))[lane];
  float4 vc = ((const float4*)(cap + (size_t)w * D))[lane];
  float ssi = vi.x*vi.x + vi.y*vi.y + vi.z*vi.z + vi.w*vi.w;
  float ssc = vc.x*vc.x + vc.y*vc.y + vc.z*vc.z + vc.w*vc.w;
  #pragma unroll
  for (int m = 1; m < 64; m <<= 1) {
    ssi += __shfl_xor(ssi, m);
    ssc += __shfl_xor(ssc, m);
  }
  float ri = 1.0f / fmaxf(sqrtf(ssi), 1e-12f);
  float rc = 1.0f / fmaxf(sqrtf(ssc), 1e-12f);
  float ax = vi.x*ri, ay = vi.y*ri, az = vi.z*ri, aw = vi.w*ri;
  float cx = vc.x*rc, cy = vc.y*rc, cz = vc.z*rc, cw = vc.w*rc;
  ushort4 ua, uc;
  ua.x = f2bf(ax); ua.y = f2bf(ay); ua.z = f2bf(az); ua.w = f2bf(aw);
  uc.x = f2bf(cx); uc.y = f2bf(cy); uc.z = f2bf(cz); uc.w = f2bf(cw);
  ((ushort4*)(imn + (size_t)w * D))[lane] = ua;
  ((ushort4*)(capn + (size_t)w * D))[lane] = uc;
  float d = ax*cx + ay*cy + az*cz + aw*cw;
  #pragma unroll
  for (int m = 1; m < 64; m <<= 1) d += __shfl_xor(d, m);
  if (lane == 0) diag[w] = d * INV_T;
}

// Kernel 2: persistent GEMM, r8 shell + m201 phase discipline.
// Grid 256 (1/CU). Block: bm (256 rows, fixed) x 4 bn-tiles of 256 cols
// (bn = grp*4+j; grp = blockIdx&7 => B-sharing blocks land on one XCD).
// A resident: 8 x [256][32] slices (128KB, staged once). B: 2 x [256][32]
// double buffer (32KB). Total exactly 160KB (r8-proven). 8 waves (2M x 4N),
// per-wave output 128x64 (acc 8x4, r5/r6-verified mapping).
// Per body (kt): {12 ds_reads; lgkmcnt(0); BAR; stage B(kt+2); setprio(1);
// 32 MFMA; setprio(0); vmcnt(2); BAR} -- reads complete before the barrier
// (cross-wave stage-overwrite safe), stage+stores fly under MFMA, vmcnt
// never drains mid-loop. 32 bodies per block.
// Swizzle (r8-verified, 0 conflicts): LDS slot(row,u) holds global
// u^((row>>1)&3); pre-swizzled source, same XOR on ds_read.
__global__ __launch_bounds__(512) void gemm_exp_kernel(
    const ushort* __restrict__ A, const ushort* __restrict__ Bm,
    float* __restrict__ rowpart, float* __restrict__ colpart, int N) {
  __shared__ ushort As[8][256 * 32];  // 128 KB: A rows [bm*256,+256), all K
  __shared__ ushort Bs[2][256 * 32];  // 32 KB: B double buffer (BK=32)
  int bm = blockIdx.x >> 3;
  int grp = blockIdx.x & 7;
  int lane = threadIdx.x & 63;
  int wv = threadIdx.x >> 6;   // 0..7
  int wm = wv >> 2;            // 0..1 : rows [wm*128, +128)
  int wn = wv & 3;             // 0..3 : cols [wn*64, +64)

  // staging geometry (r8 verbatim): srow = wv*16+(lane>>2) covers 128 rows;
  // each STAGE_* does rows srow and srow+128. LDS dest linear (lane*16B);
  // global source unit pre-swizzled (lane&3)^((lane>>3)&3).
  int srow = wv * 16 + (lane >> 2);
  int scol = 8 * ((lane & 3) ^ ((lane >> 3) & 3));
  const ushort* agS = A + ((size_t)bm * 256 + srow) * D + scol;

  f32x4 acc[8][4];

  int rb = lane & 15;
  int kb = (lane >> 4) * 8;
  int cc = kb ^ (((rb >> 1) & 3) * 8);  // swizzled read column (elems)

#define VMWAIT(n) asm volatile("s_waitcnt vmcnt(" #n ")" ::: "memory")
#define LGKM0() asm volatile("s_waitcnt lgkmcnt(0)" ::: "memory")
#define BARRIER() asm volatile("s_barrier" ::: "memory")

#define STAGE_A(c)                                                           \
  __builtin_amdgcn_global_load_lds((as1_void*)(agS + (c) * 32),              \
      (as3_void*)(&As[c][wv * 512]), 16, 0, 0);                              \
  __builtin_amdgcn_global_load_lds(                                          \
      (as1_void*)(agS + (size_t)128 * D + (c) * 32),                         \
      (as3_void*)(&As[c][4096 + wv * 512]), 16, 0, 0);

#define STAGE_B(buf, ptr, ch)                                                \
  __builtin_amdgcn_global_load_lds((as1_void*)((ptr) + (ch) * 32),           \
      (as3_void*)(&Bs[buf][wv * 512]), 16, 0, 0);                            \
  __builtin_amdgcn_global_load_lds(                                          \
      (as1_void*)((ptr) + (size_t)128 * D + (ch) * 32),                      \
      (as3_void*)(&Bs[buf][4096 + wv * 512]), 16, 0, 0);

#define READ_B(BF, buf)                                                      \
  { _Pragma("unroll") for (int ni = 0; ni < 4; ++ni)                         \
      BF[ni] = *(const bf16x8*)(&Bs[buf][(wn * 64 + ni * 16 + rb) * 32 + cc]); }

#define READ_A(AF, kt)                                                       \
  { _Pragma("unroll") for (int mi = 0; mi < 8; ++mi)                         \
      AF[mi] = *(const bf16x8*)(&As[kt][(wm * 128 + mi * 16 + rb) * 32 + cc]); }

  // Body kt: reads first (drained pre-barrier), stage + MFMA behind it.
#define BODY(KT, SPTR, SCH, CZ)                                              \
  {                                                                          \
    bf16x8 af[8], bf[4];                                                     \
    READ_B(bf, (KT) & 1)                                                     \
    READ_A(af, KT)                                                           \
    LGKM0();                                                                 \
    BARRIER();                                                               \
    STAGE_B((KT) & 1, SPTR, SCH)                                             \
    __builtin_amdgcn_s_setprio(1);                                           \
    _Pragma("unroll") for (int mi = 0; mi < 8; ++mi)                         \
      _Pragma("unroll") for (int ni = 0; ni < 4; ++ni)                       \
        acc[mi][ni] = __builtin_amdgcn_mfma_f32_16x16x32_bf16(               \
            af[mi], bf[ni],                                                  \
            (CZ) ? (f32x4){0.f, 0.f, 0.f, 0.f} : acc[mi][ni], 0, 0, 0);      \
    __builtin_amdgcn_s_setprio(0);                                           \
    VMWAIT(2); BARRIER();                                                    \
  }

#define BT(j) (Bm + ((size_t)((grp * 4 + (j)) * 256) + srow) * D + scol)

  // exp + row sums (packed butterfly, r6-verified) + direct col partials.
#define EPILOGUE(BN) {                                                        \
    _Pragma("unroll")                                                         \
    for (int mi = 0; mi < 8; ++mi)                                            \
      _Pragma("unroll")                                                       \
      for (int ni = 0; ni < 4; ++ni)                                          \
        _Pragma("unroll")                                                     \
        for (int r = 0; r < 4; ++r)                                           \
          acc[mi][ni][r] = __expf(acc[mi][ni][r] * INV_T);                    \
    bool sb0 = (lane & 1) != 0, sb1 = (lane & 2) != 0;                        \
    _Pragma("unroll")                                                         \
    for (int mi = 0; mi < 8; ++mi) {                                          \
      float v0 = acc[mi][0][0] + acc[mi][1][0] + acc[mi][2][0] + acc[mi][3][0]; \
      float v1 = acc[mi][0][1] + acc[mi][1][1] + acc[mi][2][1] + acc[mi][3][1]; \
      float v2 = acc[mi][0][2] + acc[mi][1][2] + acc[mi][2][2] + acc[mi][3][2]; \
      float v3 = acc[mi][0][3] + acc[mi][1][3] + acc[mi][2][3] + acc[mi][3][3]; \
      float h0 = (sb0 ? v1 : v0) + __shfl_xor(sb0 ? v0 : v1, 1);              \
      float h1 = (sb0 ? v3 : v2) + __shfl_xor(sb0 ? v2 : v3, 1);              \
      float g  = (sb1 ? h1 : h0) + __shfl_xor(sb1 ? h0 : h1, 2);              \
      g += __shfl_xor(g, 4);                                                  \
      g += __shfl_xor(g, 8);                                                  \
      if ((lane & 12) == 0)                                                   \
        rowpart[(size_t)((BN) * 4 + wn) * N + bm * 256 + wm * 128 + mi * 16 + \
                (lane >> 4) * 4 + (lane & 3)] = g;                            \
    }                                                                         \
    _Pragma("unroll")                                                         \
    for (int ni = 0; ni < 4; ++ni) {                                          \
      float v = 0.f;                                                          \
      _Pragma("unroll")                                                       \
      for (int mi = 0; mi < 8; ++mi)                                          \
        _Pragma("unroll")                                                     \
        for (int r = 0; r < 4; ++r)                                           \
          v += acc[mi][ni][r];                                                \
      v += __shfl_xor(v, 16); v += __shfl_xor(v, 32);                         \
      if (lane < 16)                                                          \
        colpart[(size_t)(bm * 2 + wm) * N + (BN) * 256 + wn * 64 + ni * 16 +  \
                lane] = v;                                                    \
    }                                                                         \
  }

  // Prologue: A all 8 slices (16 loads) + B(tile0,k0) + B(tile0,k1).
  STAGE_A(0) STAGE_A(1) STAGE_A(2) STAGE_A(3)
  STAGE_A(4) STAGE_A(5) STAGE_A(6) STAGE_A(7)
  STAGE_B(0, BT(0), 0)
  STAGE_B(1, BT(0), 1)
  VMWAIT(2); BARRIER();   // A + B(k0) resident; B(k1) in flight (2)

  for (int j = 0; j < 4; ++j) {
    const ushort* btc = BT(j);
    const ushort* btn = BT(j < 3 ? j + 1 : 3);  // j=3: wrap restage, never read
    // Ledger entering body 0: outstanding = B(k1)(2) [+ prior tile's stores,
    // forced complete by body 0's VMWAIT(2)].
    BODY(0, btc, 2, 1)
    BODY(1, btc, 3, 0)
    BODY(2, btc, 4, 0)
    BODY(3, btc, 5, 0)
    BODY(4, btc, 6, 0)
    BODY(5, btc, 7, 0)
    BODY(6, btn, 0, 0)   // next tile k0 -> buf0
    BODY(7, btn, 1, 0)   // next tile k1 -> buf1
    EPILOGUE(grp * 4 + j)
  }
  VMWAIT(0);  // retire wrap stages + final stores

#undef EPILOGUE
#undef BT
#undef BODY
#undef READ_A
#undef READ_B
#undef STAGE_B
#undef STAGE_A
#undef VMWAIT
#undef LGKM0
#undef BARRIER
}

// Kernel 3: partial reduction + per-sample loss + atomic accumulate into out.
__global__ __launch_bounds__(256) void reduce_kernel(
    const float* __restrict__ rowpart, const float* __restrict__ colpart,
    const float* __restrict__ diag, float* __restrict__ out,
    int N, int NPr, int NPc) {
  __shared__ float redr[4][64], redc[4][64];
  int w = threadIdx.x >> 6, s = threadIdx.x & 63;
  int i = blockIdx.x * 64 + s;
  float rs = 0.f, cs = 0.f;
  for (int k = w; k < NPr; k += 4) rs += rowpart[(size_t)k * N + i];
  for (int k = w; k < NPc; k += 4) cs += colpart[(size_t)k * N + i];
  redr[w][s] = rs; redc[w][s] = cs;
  __syncthreads();
  if (w == 0) {
    float R = redr[0][s] + redr[1][s] + redr[2][s] + redr[3][s];
    float C = redc[0][s] + redc[1][s] + redc[2][s] + redc[3][s];
    float l = logf(R) + logf(C) - 2.0f * diag[i];
    #pragma unroll
    for (int m = 1; m < 64; m <<= 1) l += __shfl_xor(l, m);
    if (s == 0) atomicAdd(out, l * (0.5f / (float)N));
  }
}

extern "C" void kernel_launch(void* const* d_in, const int* in_sizes, int n_in,
                              void* d_out, int out_size, void* d_ws, size_t ws_size,
                              hipStream_t stream) {
  const float* images = (const float*)d_in[0];
  const float* captions = (const float*)d_in[1];
  int N = in_sizes[0] / D;   // 8192
  int NPr = 128;             // 32 bn-tiles x 4 wn
  int NPc = 64;              // 32 bm-blocks x 2 wm
  char* w = (char*)d_ws;
  size_t off = 0;
  ushort* imn  = (ushort*)(w + off); off += (size_t)N * D * 2;
  ushort* capn = (ushort*)(w + off); off += (size_t)N * D * 2;
  float* diag    = (float*)(w + off); off += (size_t)N * 4;
  float* rowpart = (float*)(w + off); off += (size_t)NPr * N * 4;
  float* colpart = (float*)(w + off); off += (size_t)NPc * N * 4;
  float* out = (float*)d_out;

  normalize_kernel<<<N / 4, 256, 0, stream>>>(images, captions, imn, capn, diag, N);
  gemm_exp_kernel<<<256, 512, 0, stream>>>(imn, capn, rowpart, colpart, N);
  hipMemsetAsync(out, 0, sizeof(float), stream);
  reduce_kernel<<<N / 64, 256, 0, stream>>>(rowpart, colpart, diag, out, N, NPr, NPc);
}

// Round 14
// 68.992 us; speedup vs baseline: 1.2636x; 1.0236x over previous
//
#include <hip/hip_runtime.h>
#include <hip/hip_bf16.h>

typedef short bf16x8 __attribute__((ext_vector_type(8)));
typedef float f32x4 __attribute__((ext_vector_type(4)));

typedef __attribute__((address_space(3))) void as3_void;
typedef const __attribute__((address_space(1))) void as1_void;

static constexpr int D = 256;
static constexpr float INV_T = 10.0f;  // 1 / 0.1

__device__ __forceinline__ ushort f2bf(float f) {
  union { float f; unsigned u; } v; v.f = f;
  unsigned r = v.u + 0x7fffu + ((v.u >> 16) & 1u);  // RNE
  return (ushort)(r >> 16);
}

// Kernel 1: L2-normalize rows of images & captions -> bf16; diag logits (fp32).
__global__ __launch_bounds__(256) void normalize_kernel(
    const float* __restrict__ im, const float* __restrict__ cap,
    ushort* __restrict__ imn, ushort* __restrict__ capn,
    float* __restrict__ diag, int N) {
  int tid = blockIdx.x * 256 + threadIdx.x;
  int w = tid >> 6;
  int lane = threadIdx.x & 63;
  if (w >= N) return;
  float4 vi = ((const float4*)(im + (size_t)w * D))[lane];
  float4 vc = ((const float4*)(cap + (size_t)w * D))[lane];
  float ssi = vi.x*vi.x + vi.y*vi.y + vi.z*vi.z + vi.w*vi.w;
  float ssc = vc.x*vc.x + vc.y*vc.y + vc.z*vc.z + vc.w*vc.w;
  #pragma unroll
  for (int m = 1; m < 64; m <<= 1) {
    ssi += __shfl_xor(ssi, m);
    ssc += __shfl_xor(ssc, m);
  }
  float ri = 1.0f / fmaxf(sqrtf(ssi), 1e-12f);
  float rc = 1.0f / fmaxf(sqrtf(ssc), 1e-12f);
  float ax = vi.x*ri, ay = vi.y*ri, az = vi.z*ri, aw = vi.w*ri;
  float cx = vc.x*rc, cy = vc.y*rc, cz = vc.z*rc, cw = vc.w*rc;
  ushort4 ua, uc;
  ua.x = f2bf(ax); ua.y = f2bf(ay); ua.z = f2bf(az); ua.w = f2bf(aw);
  uc.x = f2bf(cx); uc.y = f2bf(cy); uc.z = f2bf(cz); uc.w = f2bf(cw);
  ((ushort4*)(imn + (size_t)w * D))[lane] = ua;
  ((ushort4*)(capn + (size_t)w * D))[lane] = uc;
  float d = ax*cx + ay*cy + az*cz + aw*cw;
  #pragma unroll
  for (int m = 1; m < 64; m <<= 1) d += __shfl_xor(d, m);
  if (lane == 0) diag[w] = d * INV_T;
}

// Kernel 2: persistent GEMM, r13 shell + overlapped body.
// KEY: As[] is IMMUTABLE after prologue -> A-frag reads need no barrier
// protection; B(kt+1)'s buffer is stable during body kt (staged body kt-1,
// vmcnt(0)+barrier'd). So per body: {stage B(kt+2) -> buf kt&1 (the buffer
// whose frags went to regs LAST body); read af(kt) [8, immutable] + fb(kt+1)
// [4, stable buf]; 32 MFMA on in-reg frags -- LDS service overlaps the MFMA
// region on its own pipe; lgkm0; vmcnt(0) [loads ~1300cyc old = free]; ONE
// barrier}. Reads and MFMAs of different bodies overlap; 32 barriers total.
// Shell (r13-proven): grid 256 (1/CU), bm x 4 bn-tiles, A resident 128KB,
// B dbuf 32KB = 160KB; 8 waves 2Mx4N; swizzle verified 0 conflicts.
__global__ __launch_bounds__(512) void gemm_exp_kernel(
    const ushort* __restrict__ A, const ushort* __restrict__ Bm,
    float* __restrict__ rowpart, float* __restrict__ colpart, int N) {
  __shared__ ushort As[8][256 * 32];  // 128 KB: A rows [bm*256,+256), all K
  __shared__ ushort Bs[2][256 * 32];  // 32 KB: B double buffer (BK=32)
  int bm = blockIdx.x >> 3;
  int grp = blockIdx.x & 7;   // B-sharing blocks land on one XCD (T1)
  int lane = threadIdx.x & 63;
  int wv = threadIdx.x >> 6;   // 0..7
  int wm = wv >> 2;            // 0..1 : rows [wm*128, +128)
  int wn = wv & 3;             // 0..3 : cols [wn*64, +64)

  int srow = wv * 16 + (lane >> 2);
  int scol = 8 * ((lane & 3) ^ ((lane >> 3) & 3));
  const ushort* agS = A + ((size_t)bm * 256 + srow) * D + scol;

  f32x4 acc[8][4];

  int rb = lane & 15;
  int kb = (lane >> 4) * 8;
  int cc = kb ^ (((rb >> 1) & 3) * 8);  // swizzled read column (elems)

#define VMWAIT(n) asm volatile("s_waitcnt vmcnt(" #n ")" ::: "memory")
#define LGKM0() asm volatile("s_waitcnt lgkmcnt(0)" ::: "memory")
#define BARRIER() asm volatile("s_barrier" ::: "memory")

#define STAGE_A(c)                                                           \
  __builtin_amdgcn_global_load_lds((as1_void*)(agS + (c) * 32),              \
      (as3_void*)(&As[c][wv * 512]), 16, 0, 0);                              \
  __builtin_amdgcn_global_load_lds(                                          \
      (as1_void*)(agS + (size_t)128 * D + (c) * 32),                         \
      (as3_void*)(&As[c][4096 + wv * 512]), 16, 0, 0);

#define STAGE_B(buf, ptr, ch)                                                \
  __builtin_amdgcn_global_load_lds((as1_void*)((ptr) + (ch) * 32),           \
      (as3_void*)(&Bs[buf][wv * 512]), 16, 0, 0);                            \
  __builtin_amdgcn_global_load_lds(                                          \
      (as1_void*)((ptr) + (size_t)128 * D + (ch) * 32),                      \
      (as3_void*)(&Bs[buf][4096 + wv * 512]), 16, 0, 0);

#define READ_B(BF, buf)                                                      \
  { _Pragma("unroll") for (int ni = 0; ni < 4; ++ni)                         \
      BF[ni] = *(const bf16x8*)(&Bs[buf][(wn * 64 + ni * 16 + rb) * 32 + cc]); }

#define READ_A(AF, kt)                                                       \
  { _Pragma("unroll") for (int mi = 0; mi < 8; ++mi)                         \
      AF[mi] = *(const bf16x8*)(&As[kt][(wm * 128 + mi * 16 + rb) * 32 + cc]); }

#define CLUSTER(mi, AF, FBC, CZ)                                             \
  __builtin_amdgcn_s_setprio(1);                                             \
  acc[mi][0] = __builtin_amdgcn_mfma_f32_16x16x32_bf16(AF[mi], FBC[0],       \
      (CZ) ? (f32x4){0.f,0.f,0.f,0.f} : acc[mi][0], 0, 0, 0);                \
  acc[mi][1] = __builtin_amdgcn_mfma_f32_16x16x32_bf16(AF[mi], FBC[1],       \
      (CZ) ? (f32x4){0.f,0.f,0.f,0.f} : acc[mi][1], 0, 0, 0);                \
  acc[mi][2] = __builtin_amdgcn_mfma_f32_16x16x32_bf16(AF[mi], FBC[2],       \
      (CZ) ? (f32x4){0.f,0.f,0.f,0.f} : acc[mi][2], 0, 0, 0);                \
  acc[mi][3] = __builtin_amdgcn_mfma_f32_16x16x32_bf16(AF[mi], FBC[3],       \
      (CZ) ? (f32x4){0.f,0.f,0.f,0.f} : acc[mi][3], 0, 0, 0);                \
  __builtin_amdgcn_s_setprio(0);

  // Body KT: cur B-frags FBC already in regs (read last body); stage chunk
  // SCH -> buf SCH&1 (== KT&1, whose frags were consumed-to-regs last body);
  // read af(KT) + next fb; MFMA; single drain+barrier at end.
#define BODY(KT, FBC, FBN, SPTR, SCH, CZ)                                    \
  {                                                                          \
    STAGE_B(((SCH) & 1), SPTR, SCH)                                          \
    bf16x8 af[8];                                                            \
    READ_A(af, KT)                                                           \
    READ_B(FBN, ((KT) + 1) & 1)                                              \
    CLUSTER(0, af, FBC, CZ) CLUSTER(1, af, FBC, CZ)                          \
    CLUSTER(2, af, FBC, CZ) CLUSTER(3, af, FBC, CZ)                          \
    CLUSTER(4, af, FBC, CZ) CLUSTER(5, af, FBC, CZ)                          \
    CLUSTER(6, af, FBC, CZ) CLUSTER(7, af, FBC, CZ)                          \
    LGKM0(); __builtin_amdgcn_sched_barrier(0);                              \
    VMWAIT(0); BARRIER();                                                    \
  }

#define BT(j) (Bm + ((size_t)((grp * 4 + (j)) * 256) + srow) * D + scol)

#define EPILOGUE(BN) {                                                        \
    _Pragma("unroll")                                                         \
    for (int mi = 0; mi < 8; ++mi)                                            \
      _Pragma("unroll")                                                       \
      for (int ni = 0; ni < 4; ++ni)                                          \
        _Pragma("unroll")                                                     \
        for (int r = 0; r < 4; ++r)                                           \
          acc[mi][ni][r] = __expf(acc[mi][ni][r] * INV_T);                    \
    bool sb0 = (lane & 1) != 0, sb1 = (lane & 2) != 0;                        \
    _Pragma("unroll")                                                         \
    for (int mi = 0; mi < 8; ++mi) {                                          \
      float v0 = acc[mi][0][0] + acc[mi][1][0] + acc[mi][2][0] + acc[mi][3][0]; \
      float v1 = acc[mi][0][1] + acc[mi][1][1] + acc[mi][2][1] + acc[mi][3][1]; \
      float v2 = acc[mi][0][2] + acc[mi][1][2] + acc[mi][2][2] + acc[mi][3][2]; \
      float v3 = acc[mi][0][3] + acc[mi][1][3] + acc[mi][2][3] + acc[mi][3][3]; \
      float h0 = (sb0 ? v1 : v0) + __shfl_xor(sb0 ? v0 : v1, 1);              \
      float h1 = (sb0 ? v3 : v2) + __shfl_xor(sb0 ? v2 : v3, 1);              \
      float g  = (sb1 ? h1 : h0) + __shfl_xor(sb1 ? h0 : h1, 2);              \
      g += __shfl_xor(g, 4);                                                  \
      g += __shfl_xor(g, 8);                                                  \
      if ((lane & 12) == 0)                                                   \
        rowpart[(size_t)((BN) * 4 + wn) * N + bm * 256 + wm * 128 + mi * 16 + \
                (lane >> 4) * 4 + (lane & 3)] = g;                            \
    }                                                                         \
    _Pragma("unroll")                                                         \
    for (int ni = 0; ni < 4; ++ni) {                                          \
      float v = 0.f;                                                          \
      _Pragma("unroll")                                                       \
      for (int mi = 0; mi < 8; ++mi)                                          \
        _Pragma("unroll")                                                     \
        for (int r = 0; r < 4; ++r)                                           \
          v += acc[mi][ni][r];                                                \
      v += __shfl_xor(v, 16); v += __shfl_xor(v, 32);                         \
      if (lane < 16)                                                          \
        colpart[(size_t)(bm * 2 + wm) * N + (BN) * 256 + wn * 64 + ni * 16 +  \
                lane] = v;                                                    \
    }                                                                         \
  }

  // Prologue: A all 8 slices + B(tile0, chunks 0,1); full drain once.
  STAGE_A(0) STAGE_A(1) STAGE_A(2) STAGE_A(3)
  STAGE_A(4) STAGE_A(5) STAGE_A(6) STAGE_A(7)
  STAGE_B(0, BT(0), 0)
  STAGE_B(1, BT(0), 1)
  VMWAIT(0); BARRIER();

  bf16x8 fbA[4], fbB[4];
  READ_B(fbA, 0)   // chunk-0 frags for body 0 (lgkm auto-waited before MFMA)

  for (int j = 0; j < 4; ++j) {
    const ushort* btc = BT(j);
    const ushort* btn = BT(j < 3 ? j + 1 : 3);  // j=3: wrap restage, never used
    BODY(0, fbA, fbB, btc, 2, 1)
    BODY(1, fbB, fbA, btc, 3, 0)
    BODY(2, fbA, fbB, btc, 4, 0)
    BODY(3, fbB, fbA, btc, 5, 0)
    BODY(4, fbA, fbB, btc, 6, 0)
    BODY(5, fbB, fbA, btc, 7, 0)
    BODY(6, fbA, fbB, btn, 0, 0)   // next-tile chunk0 -> buf0
    BODY(7, fbB, fbA, btn, 1, 0)   // next-tile chunk1 -> buf1
    EPILOGUE(grp * 4 + j)
  }
  VMWAIT(0);  // retire wrap stages + final stores

#undef EPILOGUE
#undef BT
#undef BODY
#undef CLUSTER
#undef READ_A
#undef READ_B
#undef STAGE_B
#undef STAGE_A
#undef VMWAIT
#undef LGKM0
#undef BARRIER
}

// Kernel 3: partial reduction + per-sample loss + atomic accumulate into out.
__global__ __launch_bounds__(256) void reduce_kernel(
    const float* __restrict__ rowpart, const float* __restrict__ colpart,
    const float* __restrict__ diag, float* __restrict__ out,
    int N, int NPr, int NPc) {
  __shared__ float redr[4][64], redc[4][64];
  int w = threadIdx.x >> 6, s = threadIdx.x & 63;
  int i = blockIdx.x * 64 + s;
  float rs = 0.f, cs = 0.f;
  for (int k = w; k < NPr; k += 4) rs += rowpart[(size_t)k * N + i];
  for (int k = w; k < NPc; k += 4) cs += colpart[(size_t)k * N + i];
  redr[w][s] = rs; redc[w][s] = cs;
  __syncthreads();
  if (w == 0) {
    float R = redr[0][s] + redr[1][s] + redr[2][s] + redr[3][s];
    float C = redc[0][s] + redc[1][s] + redc[2][s] + redc[3][s];
    float l = logf(R) + logf(C) - 2.0f * diag[i];
    #pragma unroll
    for (int m = 1; m < 64; m <<= 1) l += __shfl_xor(l, m);
    if (s == 0) atomicAdd(out, l * (0.5f / (float)N));
  }
}

extern "C" void kernel_launch(void* const* d_in, const int* in_sizes, int n_in,
                              void* d_out, int out_size, void* d_ws, size_t ws_size,
                              hipStream_t stream) {
  const float* images = (const float*)d_in[0];
  const float* captions = (const float*)d_in[1];
  int N = in_sizes[0] / D;   // 8192
  int NPr = 128;             // 32 bn-tiles x 4 wn
  int NPc = 64;              // 32 bm-blocks x 2 wm
  char* w = (char*)d_ws;
  size_t off = 0;
  ushort* imn  = (ushort*)(w + off); off += (size_t)N * D * 2;
  ushort* capn = (ushort*)(w + off); off += (size_t)N * D * 2;
  float* diag    = (float*)(w + off); off += (size_t)N * 4;
  float* rowpart = (float*)(w + off); off += (size_t)NPr * N * 4;
  float* colpart = (float*)(w + off); off += (size_t)NPc * N * 4;
  float* out = (float*)d_out;

  normalize_kernel<<<N / 4, 256, 0, stream>>>(images, captions, imn, capn, diag, N);
  gemm_exp_kernel<<<256, 512, 0, stream>>>(imn, capn, rowpart, colpart, N);
  hipMemsetAsync(out, 0, sizeof(float), stream);
  reduce_kernel<<<N / 64, 256, 0, stream>>>(rowpart, colpart, diag, out, N, NPr, NPc);
}